// Round 18
// baseline (376.288 us; speedup 1.0000x reference)
//
#include <hip/hip_runtime.h>

#define NN 20000
#define NE 640000
#define NR 8
#define NB 8
#define HID 256
#define KPOI 12
#define KTIME 2880
#define KROAD 128
#define NK (NN * NR)    // 160000 (dst,rel) keys
#define NS 9            // 8 relations + self
#define KCAT (NS * HID) // 2304
#define SPLITK 5
#define KCH (KTIME / SPLITK)   // 576 = 9 x 64

typedef __attribute__((ext_vector_type(8))) short bf8_t;   // 8 bf16 = 4 VGPR
typedef __attribute__((ext_vector_type(4))) float f4_t;

__device__ inline unsigned short f2bf(float f) {  // RNE f32->bf16
  unsigned int u = __float_as_uint(f);
  u += 0x7FFF + ((u >> 16) & 1);
  return (unsigned short)(u >> 16);
}
__device__ inline float bf2f(unsigned short h) {
  return __uint_as_float((unsigned int)h << 16);
}

// async global->LDS, 16B per lane; LDS dest = wave-uniform base + lane*16
__device__ inline void gl_lds16(const void* g, void* l) {
  __builtin_amdgcn_global_load_lds(
      (const __attribute__((address_space(1))) void*)g,
      (__attribute__((address_space(3))) void*)l, 16, 0, 0);
}

// ---------------- f32 GEMM tile body (poi/road projections) ----------------
#define BK 16
__device__ inline void sgemm_body(
    int M, int Nn, int K,
    const float* __restrict__ A, int lda,
    const float* __restrict__ B, int ldb,
    const float* __restrict__ bias,
    unsigned short* __restrict__ C, int ldc, int brow, char* lds)
{
  constexpr int BM = 64, BN = 64, TM = 4, TN = 4;
  constexpr int SA = BM + 4;
  constexpr int SB = BN + 4;
  float* As = (float*)lds;
  float* Bs = (float*)(lds + 4352);
  const int tid = threadIdx.x;
  constexpr int TCOLS = BN / TN;
  const int row0 = (tid / TCOLS) * TM;
  const int col0 = (tid % TCOLS) * TN;

  float acc[TM][TN] = {};

  for (int kb = 0; kb < K; kb += BK) {
    {
      int i = tid;
      int r = i >> 2, q = (i & 3) * 4;
      int grow = brow + r, gk = kb + q;
      if (grow < M && gk + 3 < K) {
        float4 v = *(const float4*)(A + (size_t)grow * lda + gk);
        As[(q + 0) * SA + r] = v.x;
        As[(q + 1) * SA + r] = v.y;
        As[(q + 2) * SA + r] = v.z;
        As[(q + 3) * SA + r] = v.w;
      } else {
#pragma unroll
        for (int j = 0; j < 4; ++j)
          As[(q + j) * SA + r] =
              (grow < M && gk + j < K) ? A[(size_t)grow * lda + gk + j] : 0.f;
      }
    }
    {
      int i = tid;
      int k = i / (BN / 4), cq = (i % (BN / 4)) * 4;
      int gk = kb + k;
      float4 v = {0.f, 0.f, 0.f, 0.f};
      if (gk < K) {
        if (cq + 3 < Nn) {
          v = *(const float4*)(B + (size_t)gk * ldb + cq);
        } else {
#pragma unroll
          for (int j = 0; j < 4; ++j)
            if (cq + j < Nn) (&v.x)[j] = B[(size_t)gk * ldb + cq + j];
        }
      }
      *(float4*)(&Bs[k * SB + cq]) = v;
    }
    __syncthreads();
#pragma unroll
    for (int kk = 0; kk < BK; ++kk) {
      float a[TM], bb[TN];
      *(float4*)(&a[0]) = *(const float4*)(&As[kk * SA + row0]);
      *(float4*)(&bb[0]) = *(const float4*)(&Bs[kk * SB + col0]);
#pragma unroll
      for (int i = 0; i < TM; ++i)
#pragma unroll
        for (int j = 0; j < TN; ++j)
          acc[i][j] += a[i] * bb[j];
    }
    __syncthreads();
  }

  float bcache[TN];
#pragma unroll
  for (int j = 0; j < TN; ++j) bcache[j] = bias[col0 + j];
#pragma unroll
  for (int i = 0; i < TM; ++i) {
    int row = brow + row0 + i;
    if (row >= M) continue;
#pragma unroll
    for (int j = 0; j < TN; ++j)
      C[(size_t)row * ldc + col0 + j] = f2bf(acc[i][j] + bcache[j]);
  }
}

// ---------------- merged hist + weight-prep + poi/road projections ---------
__global__ __launch_bounds__(256) void hist_prep_k(
    const int* __restrict__ dstp, const int* __restrict__ etp,
    int* __restrict__ counts,
    const float* __restrict__ loop_w1, const float* __restrict__ loop_w2,
    const float* __restrict__ time_w,
    const float* __restrict__ coef1, const float* __restrict__ basis1,
    const float* __restrict__ coef2, const float* __restrict__ basis2,
    const float* __restrict__ poi_dist, const float* __restrict__ poi_w,
    const float* __restrict__ poi_b,
    const float* __restrict__ road_feat, const float* __restrict__ road_w,
    const float* __restrict__ road_b,
    unsigned short* __restrict__ Wc1, unsigned short* __restrict__ Wc2,
    unsigned short* __restrict__ TWT, unsigned short* __restrict__ hbuf)
{
  __shared__ __align__(16) char lds[8704];
  int b = blockIdx.x;
  if (b < 2500) {   // histogram: 2500*256 == NE exactly
    int e = b * 256 + threadIdx.x;
    atomicAdd(&counts[dstp[e] * NR + etp[e]], 1);
    return;
  }
  b -= 2500;
  const int to = threadIdx.x & 63;
  const int tq = threadIdx.x >> 6;

  if (b < 378) {
    unsigned short (*T)[66] = (unsigned short (*)[66])lds;
    if (b < 256) {        // Wc[lr][o][r*256+i] = sum_q coef*basis[q][i][o]
      const int lr = b >> 4;
      const int tile = b & 15;
      const int i0 = ((tile >> 2) & 3) * 64, o0 = (tile & 3) * 64;
      const float* coef  = (lr < NR) ? coef1 : coef2;
      const float* basis = (lr < NR) ? basis1 : basis2;
      unsigned short* Wc = (lr < NR) ? Wc1 : Wc2;
      const int r = lr & 7;
      float cf[NB];
#pragma unroll
      for (int q = 0; q < NB; ++q) cf[q] = coef[r * NB + q];
#pragma unroll
      for (int k = 0; k < 16; ++k) {
        int i_loc = tq * 16 + k;
        int i = i0 + i_loc;
        float acc = 0.f;
#pragma unroll
        for (int q = 0; q < NB; ++q)
          acc += cf[q] * basis[((size_t)(q * HID + i)) * HID + o0 + to];
        T[i_loc][to] = f2bf(acc);
      }
      __syncthreads();
#pragma unroll
      for (int k = 0; k < 16; ++k) {
        int o_loc = tq * 16 + k;
        Wc[(size_t)(o0 + o_loc) * KCAT + r * HID + i0 + to] = T[to][o_loc];
      }
    } else if (b < 288) { // Wc[l][o][2048+i] = loop_w_l[i][o]
      const int j = b - 256;
      const int layer = j >> 4;
      const int tile = j & 15;
      const int i0 = ((tile >> 2) & 3) * 64, o0 = (tile & 3) * 64;
      const float* lw = layer ? loop_w2 : loop_w1;
      unsigned short* Wc = layer ? Wc2 : Wc1;
#pragma unroll
      for (int k = 0; k < 16; ++k) {
        int i_loc = tq * 16 + k;
        T[i_loc][to] = f2bf(lw[(size_t)(i0 + i_loc) * HID + o0 + to]);
      }
      __syncthreads();
#pragma unroll
      for (int k = 0; k < 16; ++k) {
        int o_loc = tq * 16 + k;
        Wc[(size_t)(o0 + o_loc) * KCAT + NR * HID + i0 + to] = T[to][o_loc];
      }
    } else {              // TWT[c][r] = time_w[r][c], tiled 64x64
      const int j = b - 288;
      const int r0 = (j >> 1) * 64, c0 = (j & 1) * 64;
#pragma unroll
      for (int k = 0; k < 16; ++k) {
        int r_loc = tq * 16 + k;
        T[r_loc][to] = f2bf(time_w[(size_t)(r0 + r_loc) * 128 + c0 + to]);
      }
      __syncthreads();
#pragma unroll
      for (int k = 0; k < 16; ++k) {
        int c_loc = tq * 16 + k;
        TWT[(size_t)(c0 + c_loc) * KTIME + r0 + to] = T[to][c_loc];
      }
    }
  } else if (b < 691) {   // poi projection -> hbuf cols [0,64)
    sgemm_body(NN, 64, KPOI, poi_dist, KPOI, poi_w, 64, poi_b,
               hbuf + 0, HID, (b - 378) * 64, lds);
  } else {                // road projection -> hbuf cols [192,256)
    sgemm_body(NN, 64, KROAD, road_feat, KROAD, road_w, 64, road_b,
               hbuf + 192, HID, (b - 691) * 64, lds);
  }
}

// ---------------- merged scan: parallel cross-block base -------------------
__global__ __launch_bounds__(256) void scan_all(
    const int* __restrict__ counts, int* __restrict__ offs,
    int* __restrict__ cursor, int* __restrict__ bsums,
    int* __restrict__ counter) {
  __shared__ int sh[256];
  const int bid = blockIdx.x;
  const int t = threadIdx.x;
  const int nblk = gridDim.x;
  const int gbase = bid * 1024;
  int v[4], run[4];
  int s = 0;
#pragma unroll
  for (int j = 0; j < 4; ++j) {
    int idx = gbase + t * 4 + j;
    v[j] = (idx < NK) ? counts[idx] : 0;
    s += v[j];
  }
  sh[t] = s;
  __syncthreads();
  for (int off = 1; off < 256; off <<= 1) {
    int x = (t >= off) ? sh[t - off] : 0;
    __syncthreads();
    sh[t] += x;
    __syncthreads();
  }
  {
    int r = sh[t] - s;
#pragma unroll
    for (int j = 0; j < 4; ++j) { run[j] = r; r += v[j]; }
  }
  if (t == 255) {
    bsums[bid] = sh[255];
    __threadfence();
    atomicAdd(counter, 1);
  }
  if (t == 0) {
    while (atomicAdd(counter, 0) < nblk) {}
    __threadfence();
  }
  __syncthreads();
  int bs = (t < nblk) ? atomicAdd(&bsums[t], 0) : 0;
  __syncthreads();
  sh[t] = bs;
  __syncthreads();
  for (int off = 1; off < 256; off <<= 1) {
    int x = (t >= off) ? sh[t - off] : 0;
    __syncthreads();
    sh[t] += x;
    __syncthreads();
  }
  const int base = (bid > 0) ? sh[bid - 1] : 0;
#pragma unroll
  for (int j = 0; j < 4; ++j) {
    int idx = gbase + t * 4 + j;
    if (idx < NK) {
      int val = run[j] + base;
      offs[idx] = val;
      cursor[idx] = val;
    }
  }
  if (bid == 0 && t == 0) offs[NK] = NE;
}

// ---------------- merged cross-block split-K time GEMM + CSR fill ----------
__global__ __launch_bounds__(256) void time_fill_k(
    const int* __restrict__ srcp, const int* __restrict__ dstp,
    const int* __restrict__ etp, int* __restrict__ cursor,
    unsigned short* __restrict__ ssrc,
    const float* __restrict__ A,            // [NN][2880] f32
    const unsigned short* __restrict__ BT,  // [128][2880] bf16
    float* __restrict__ TP)                 // [SPLITK][NN][128] f32 partials
{
  __shared__ __align__(16) char lds[20480];
  const int b = blockIdx.x;
  const int grp = b / 9, rem = b % 9;
  if (rem >= 5) {   // ---- fill role ----
    int e = (grp * 4 + (rem - 5)) * 256 + threadIdx.x;   // < 640000 exact
    int key = dstp[e] * NR + etp[e];
    int p = atomicAdd(&cursor[key], 1);
    ssrc[p] = (unsigned short)srcp[e];
    return;
  }
  // ---- sk role: rows grp*32..+31, K-chunk rem ----
  char* ldsA = lds;            // 4 KB
  char* ldsB = lds + 4096;     // 16 KB
  const int tid = threadIdx.x;
  const int lane = tid & 63;
  const int w = tid >> 6;            // 0..3 -> col block w*32
  const int brow = grp * 32;
  const int kb0 = rem * KCH;

  f4_t acc[2][2];
#pragma unroll
  for (int i = 0; i < 2; ++i)
#pragma unroll
    for (int j = 0; j < 2; ++j) acc[i][j] = (f4_t){0.f, 0.f, 0.f, 0.f};

  for (int kb = kb0; kb < kb0 + KCH; kb += 64) {
    {  // A: 32 rows x 64 k, f32 -> bf16
      int r = tid >> 3, c8 = tid & 7;
      const float* ap = A + (size_t)(brow + r) * KTIME + kb + c8 * 8;
      f4_t v0 = *(const f4_t*)ap;
      f4_t v1 = *(const f4_t*)(ap + 4);
      unsigned short hh[8];
#pragma unroll
      for (int j = 0; j < 4; ++j) { hh[j] = f2bf(v0[j]); hh[4 + j] = f2bf(v1[j]); }
      *(bf8_t*)(ldsA + r * 128 + ((c8 * 16) ^ ((r & 7) << 4))) = *(bf8_t*)hh;
    }
#pragma unroll
    for (int it = 0; it < 4; ++it) {  // B: 128 rows x 64 k
      int slot = tid + it * 256;
      int r = slot >> 3, c8 = slot & 7;
      bf8_t v = *(const bf8_t*)(BT + (size_t)r * KTIME + kb + c8 * 8);
      *(bf8_t*)(ldsB + r * 128 + ((c8 * 16) ^ ((r & 7) << 4))) = v;
    }
    __syncthreads();
#pragma unroll
    for (int ks = 0; ks < 2; ++ks) {
      const int kbyte = ks * 64 + (lane >> 4) * 16;
      bf8_t af[2], bfr[2];
#pragma unroll
      for (int mi = 0; mi < 2; ++mi) {
        int m = mi * 16 + (lane & 15);
        af[mi] = *(const bf8_t*)(ldsA + m * 128 + (kbyte ^ ((m & 7) << 4)));
      }
#pragma unroll
      for (int ni = 0; ni < 2; ++ni) {
        int n = w * 32 + ni * 16 + (lane & 15);
        bfr[ni] = *(const bf8_t*)(ldsB + n * 128 + (kbyte ^ ((n & 7) << 4)));
      }
#pragma unroll
      for (int mi = 0; mi < 2; ++mi)
#pragma unroll
        for (int ni = 0; ni < 2; ++ni)
          acc[mi][ni] = __builtin_amdgcn_mfma_f32_16x16x32_bf16(
              af[mi], bfr[ni], acc[mi][ni], 0, 0, 0);
    }
    __syncthreads();
  }

  float* tp = TP + (size_t)rem * NN * 128;
  const int rq = (lane >> 4) * 4;
  const int cl = lane & 15;
#pragma unroll
  for (int ni = 0; ni < 2; ++ni) {
    int c = w * 32 + ni * 16 + cl;
#pragma unroll
    for (int mi = 0; mi < 2; ++mi) {
#pragma unroll
      for (int j = 0; j < 4; ++j) {
        int row = brow + mi * 16 + rq + j;
        tp[(size_t)row * 128 + c] = acc[mi][ni][j];
      }
    }
  }
}

// ---------------- time finish: hbuf[:,64:192] = bf16(sum_k TP + bias) ------
__global__ __launch_bounds__(256) void time_finish(
    const float* __restrict__ TP, const float* __restrict__ bias,
    unsigned short* __restrict__ featb) {
  int i = blockIdx.x * 256 + threadIdx.x;   // over NN*32 float4 groups
  if (i >= NN * 32) return;
  int row = i >> 5, c4 = (i & 31) * 4;
  f4_t s = *(const f4_t*)(TP + (size_t)row * 128 + c4);
#pragma unroll
  for (int k = 1; k < SPLITK; ++k) {
    f4_t v = *(const f4_t*)(TP + (size_t)k * NN * 128 + (size_t)row * 128 + c4);
    s.x += v.x; s.y += v.y; s.z += v.z; s.w += v.w;
  }
  f4_t b = *(const f4_t*)(bias + c4);
  unsigned short h[4] = {f2bf(s.x + b.x), f2bf(s.y + b.y),
                         f2bf(s.z + b.z), f2bf(s.w + b.w)};
  *(ushort4*)(featb + (size_t)row * 256 + 64 + c4) = *(ushort4*)h;
}

// ---------------- CSR aggregation: TWO waves per dst ------------------------
// wave half 0: slices 0..3; half 1: slices 4..7 + self copy. 40000 waves.
__global__ __launch_bounds__(256) void agg_k(
    const int* __restrict__ offs, const unsigned short* __restrict__ ssrc,
    const unsigned short* __restrict__ hin, unsigned short* __restrict__ Zc) {
  int gw = (blockIdx.x * 256 + threadIdx.x) >> 6;
  int lane = threadIdx.x & 63;
  if (gw >= 2 * NN) return;
  int d = gw >> 1;
  int half = gw & 1;
  unsigned short* zrow = Zc + (size_t)d * KCAT;
  if (half) {   // self slice
    *(ushort4*)(zrow + NR * HID + lane * 4) =
        *(const ushort4*)(hin + (size_t)d * HID + lane * 4);
  }
  const int q0 = half * 4;
  int ob[5];
#pragma unroll
  for (int r = 0; r <= 4; ++r) ob[r] = offs[d * NR + q0 + r];
#pragma unroll 1
  for (int q = 0; q < 4; ++q) {
    int e = ob[q], hi = ob[q + 1];
    f4_t az = {0.f, 0.f, 0.f, 0.f};
    for (; e + 4 <= hi; e += 4) {
      int s0 = ssrc[e], s1 = ssrc[e + 1], s2 = ssrc[e + 2], s3 = ssrc[e + 3];
      ushort4 u0 = *(const ushort4*)(hin + (size_t)s0 * HID + lane * 4);
      ushort4 u1 = *(const ushort4*)(hin + (size_t)s1 * HID + lane * 4);
      ushort4 u2 = *(const ushort4*)(hin + (size_t)s2 * HID + lane * 4);
      ushort4 u3 = *(const ushort4*)(hin + (size_t)s3 * HID + lane * 4);
      az.x += (bf2f(u0.x) + bf2f(u1.x)) + (bf2f(u2.x) + bf2f(u3.x));
      az.y += (bf2f(u0.y) + bf2f(u1.y)) + (bf2f(u2.y) + bf2f(u3.y));
      az.z += (bf2f(u0.z) + bf2f(u1.z)) + (bf2f(u2.z) + bf2f(u3.z));
      az.w += (bf2f(u0.w) + bf2f(u1.w)) + (bf2f(u2.w) + bf2f(u3.w));
    }
    for (; e < hi; ++e) {
      int s = ssrc[e];
      ushort4 u = *(const ushort4*)(hin + (size_t)s * HID + lane * 4);
      az.x += bf2f(u.x); az.y += bf2f(u.y);
      az.z += bf2f(u.z); az.w += bf2f(u.w);
    }
    unsigned short hz[4] = {f2bf(az.x), f2bf(az.y), f2bf(az.z), f2bf(az.w)};
    *(ushort4*)(zrow + (q0 + q) * HID + lane * 4) = *(ushort4*)hz;
  }
}

// ---------------- layer GEMM: 2-phase double-buffered (T3-minimum) ---------
// stage(t+1) issued BEFORE compute(t); ONE __syncthreads per iter.
template<int EPI>
__global__ __launch_bounds__(512) void gemm_cat(
    const unsigned short* __restrict__ Zc,    // [NN][KCAT]
    const unsigned short* __restrict__ Wc,    // [256][KCAT]
    const float* __restrict__ bias,
    float* __restrict__ C, unsigned short* __restrict__ hb)
{
  __shared__ __align__(16) char At[2][64 * 128];    // 16 KB
  __shared__ __align__(16) char Bt[2][256 * 128];   // 64 KB
  const int tid = threadIdx.x;
  const int lane = tid & 63;
  const int w = tid >> 6;
  const int wm = w >> 2;         // rows wm*32..+31
  const int wn = w & 3;          // cols wn*64..+63
  const int brow = blockIdx.x * 64;
  const bool full = (brow + 64 <= NN);
  const int c8sw = (lane & 7) ^ (lane >> 3);

  f4_t acc[2][4];
#pragma unroll
  for (int i = 0; i < 2; ++i)
#pragma unroll
    for (int j = 0; j < 4; ++j) acc[i][j] = (f4_t){0.f, 0.f, 0.f, 0.f};

  auto stage = [&](int buf, int kb) {
    if (full) {  // A via global_load_lds: wave w -> rows w*8..w*8+7
      int row = (w << 3) + (lane >> 3);
      gl_lds16(Zc + (size_t)(brow + row) * KCAT + kb + c8sw * 8,
               At[buf] + (w << 10));
    } else {     // guarded reg-staged fallback (last block only)
      int r = tid >> 3, c8 = tid & 7;
      int grow = brow + r;
      bf8_t v = {0, 0, 0, 0, 0, 0, 0, 0};
      if (grow < NN) v = *(const bf8_t*)(Zc + (size_t)grow * KCAT + kb + c8 * 8);
      *(bf8_t*)(At[buf] + r * 128 + ((c8 * 16) ^ ((r & 7) << 4))) = v;
    }
#pragma unroll
    for (int it = 0; it < 4; ++it) {  // B via global_load_lds
      int n0 = (w << 3) + it * 64;
      int n = n0 + (lane >> 3);
      gl_lds16(Wc + (size_t)n * KCAT + kb + c8sw * 8, Bt[buf] + n0 * 128);
    }
  };

  stage(0, 0);
  __syncthreads();

  constexpr int NT = KCAT / 64;   // 36
#pragma unroll 1
  for (int t = 0; t < NT; ++t) {
    const int cur = t & 1;
    if (t + 1 < NT) stage(cur ^ 1, (t + 1) * 64);   // in flight during compute
#pragma unroll
    for (int ks = 0; ks < 2; ++ks) {
      const int kbyte = ks * 64 + (lane >> 4) * 16;
      bf8_t af[2], bfr[4];
#pragma unroll
      for (int mi = 0; mi < 2; ++mi) {
        int m = wm * 32 + mi * 16 + (lane & 15);
        af[mi] = *(const bf8_t*)(At[cur] + m * 128 + (kbyte ^ ((m & 7) << 4)));
      }
#pragma unroll
      for (int ni = 0; ni < 4; ++ni) {
        int n = wn * 64 + ni * 16 + (lane & 15);
        bfr[ni] = *(const bf8_t*)(Bt[cur] + n * 128 + (kbyte ^ ((n & 7) << 4)));
      }
#pragma unroll
      for (int mi = 0; mi < 2; ++mi)
#pragma unroll
        for (int ni = 0; ni < 4; ++ni)
          acc[mi][ni] = __builtin_amdgcn_mfma_f32_16x16x32_bf16(
              af[mi], bfr[ni], acc[mi][ni], 0, 0, 0);
    }
    __syncthreads();   // next-tile loads landed + all waves done reading cur
  }

  const int rq = (lane >> 4) * 4;
  const int cl = lane & 15;
#pragma unroll
  for (int ni = 0; ni < 4; ++ni) {
    int c = wn * 64 + ni * 16 + cl;
    float bv = bias[c];
#pragma unroll
    for (int mi = 0; mi < 2; ++mi) {
#pragma unroll
      for (int j = 0; j < 4; ++j) {
        int row = brow + wm * 32 + mi * 16 + rq + j;
        if (row < NN) {
          size_t o = (size_t)row * HID + c;
          float v = acc[mi][ni][j] + bv;
          if (EPI == 0) C[o] = v;
          else          hb[o] = f2bf(fmaxf(v, 0.f));
        }
      }
    }
  }
}

extern "C" void kernel_launch(void* const* d_in, const int* in_sizes, int n_in,
                              void* d_out, int out_size, void* d_ws, size_t ws_size,
                              hipStream_t stream) {
  const int*   srcp      = (const int*)d_in[0];
  const int*   dstp      = (const int*)d_in[1];
  const int*   etypep    = (const int*)d_in[2];
  const float* poi_dist  = (const float*)d_in[3];
  const float* time_dist = (const float*)d_in[4];
  const float* road_feat = (const float*)d_in[5];
  const float* poi_w     = (const float*)d_in[6];
  const float* poi_b     = (const float*)d_in[7];
  const float* time_w    = (const float*)d_in[8];
  const float* time_b    = (const float*)d_in[9];
  const float* road_w    = (const float*)d_in[10];
  const float* road_b    = (const float*)d_in[11];
  const float* basis1    = (const float*)d_in[12];
  const float* coef1     = (const float*)d_in[13];
  const float* loop_w1   = (const float*)d_in[14];
  const float* bias1     = (const float*)d_in[15];
  const float* basis2    = (const float*)d_in[16];
  const float* coef2     = (const float*)d_in[17];
  const float* loop_w2   = (const float*)d_in[18];
  const float* bias2     = (const float*)d_in[19];

  float* out = (float*)d_out;

  // ws layout (bytes), total ~108.1 MB (ws_size ~921 MB):
  //   Wc1  bf16 @ 0           (1,179,648)   [256][2304]
  //   Wc2  bf16 @ 1,179,648   (1,179,648)
  //   TWT  bf16 @ 2,359,296   (737,280)
  //   hbuf bf16 @ 3,096,576   (10,240,000)  feat; then relu(h1)
  //   Zcat bf16 @ 13,336,576  (92,160,000)  [NN][2304]
  //   offs      @ 105,496,576 (640,016)
  //   bsums     @ 106,136,592 (1,024)
  //   ssrc u16  @ 106,137,616 (1,280,000)
  //   cursor    @ 107,417,616 (640,000)
  // aliases into Zcat region (each dead before Zcat's first write by agg):
  //   counts (NK ints) + counter @ Zcat base; TP f32 (51.2 MB) @ Zcat base
  char* ws = (char*)d_ws;
  unsigned short* Wc1    = (unsigned short*)(ws);
  unsigned short* Wc2    = (unsigned short*)(ws + 1179648);
  unsigned short* TWT    = (unsigned short*)(ws + 2359296);
  unsigned short* hbuf   = (unsigned short*)(ws + 3096576);
  unsigned short* Zcat   = (unsigned short*)(ws + 13336576);
  int*            offs   = (int*)  (ws + 105496576);
  int*            bsums  = (int*)  (ws + 106136592);
  unsigned short* ssrc   = (unsigned short*)(ws + 106137616);
  int*            cursor = (int*)  (ws + 107417616);
  int*            counts = (int*)Zcat;        // NK ints
  int*            counter = counts + NK;      // 1 int (spin counter)
  float*          TP     = (float*)Zcat;      // [SPLITK][NN][128], after scan

  dim3 blk(256);

  // ---- zero counts + counter ----
  hipMemsetAsync(counts, 0, (NK + 1) * sizeof(int), stream);

  // ---- hist (2500 blocks) || weight prep + poi/road projections (1004) ----
  hist_prep_k<<<3504, blk, 0, stream>>>(dstp, etypep, counts,
                                        loop_w1, loop_w2, time_w,
                                        coef1, basis1, coef2, basis2,
                                        poi_dist, poi_w, poi_b,
                                        road_feat, road_w, road_b,
                                        Wc1, Wc2, TWT, hbuf);

  // ---- scan (157 resident blocks, parallel cross-block base) ----
  scan_all<<<(NK + 1023) / 1024, blk, 0, stream>>>(counts, offs, cursor,
                                                   bsums, counter);

  // ---- cross-block split-K time GEMM (3125) || CSR fill (2500), interleaved
  time_fill_k<<<5625, blk, 0, stream>>>(srcp, dstp, etypep, cursor, ssrc,
                                        time_dist, TWT, TP);
  time_finish<<<(NN * 32 + 255) / 256, blk, 0, stream>>>(TP, time_b, hbuf);

  // ---- layer 1 ----
  agg_k<<<(2 * NN * 64) / 256, blk, 0, stream>>>(offs, ssrc, hbuf, Zcat);
  gemm_cat<1><<<(NN + 63) / 64, 512, 0, stream>>>(Zcat, Wc1, bias1, nullptr, hbuf);

  // ---- layer 2 ----
  agg_k<<<(2 * NN * 64) / 256, blk, 0, stream>>>(offs, ssrc, hbuf, Zcat);
  gemm_cat<0><<<(NN + 63) / 64, 512, 0, stream>>>(Zcat, Wc2, bias2, out, nullptr);
}

// Round 19
// 369.538 us; speedup vs baseline: 1.0183x; 1.0183x over previous
//
#include <hip/hip_runtime.h>

#define NN 20000
#define NE 640000
#define NR 8
#define NB 8
#define HID 256
#define KPOI 12
#define KTIME 2880
#define KROAD 128
#define NK (NN * NR)    // 160000 (dst,rel) keys
#define NS 9            // 8 relations + self
#define KCAT (NS * HID) // 2304
#define SPLITK 5
#define KCH (KTIME / SPLITK)   // 576 = 9 x 64

typedef __attribute__((ext_vector_type(8))) short bf8_t;   // 8 bf16 = 4 VGPR
typedef __attribute__((ext_vector_type(4))) float f4_t;

__device__ inline unsigned short f2bf(float f) {  // RNE f32->bf16
  unsigned int u = __float_as_uint(f);
  u += 0x7FFF + ((u >> 16) & 1);
  return (unsigned short)(u >> 16);
}
__device__ inline float bf2f(unsigned short h) {
  return __uint_as_float((unsigned int)h << 16);
}

// async global->LDS, 16B per lane; LDS dest = wave-uniform base + lane*16
__device__ inline void gl_lds16(const void* g, void* l) {
  __builtin_amdgcn_global_load_lds(
      (const __attribute__((address_space(1))) void*)g,
      (__attribute__((address_space(3))) void*)l, 16, 0, 0);
}

// ---------------- f32 GEMM tile body (poi/road projections) ----------------
#define BK 16
__device__ inline void sgemm_body(
    int M, int Nn, int K,
    const float* __restrict__ A, int lda,
    const float* __restrict__ B, int ldb,
    const float* __restrict__ bias,
    unsigned short* __restrict__ C, int ldc, int brow, char* lds)
{
  constexpr int BM = 64, BN = 64, TM = 4, TN = 4;
  constexpr int SA = BM + 4;
  constexpr int SB = BN + 4;
  float* As = (float*)lds;
  float* Bs = (float*)(lds + 4352);
  const int tid = threadIdx.x;
  constexpr int TCOLS = BN / TN;
  const int row0 = (tid / TCOLS) * TM;
  const int col0 = (tid % TCOLS) * TN;

  float acc[TM][TN] = {};

  for (int kb = 0; kb < K; kb += BK) {
    {
      int i = tid;
      int r = i >> 2, q = (i & 3) * 4;
      int grow = brow + r, gk = kb + q;
      if (grow < M && gk + 3 < K) {
        float4 v = *(const float4*)(A + (size_t)grow * lda + gk);
        As[(q + 0) * SA + r] = v.x;
        As[(q + 1) * SA + r] = v.y;
        As[(q + 2) * SA + r] = v.z;
        As[(q + 3) * SA + r] = v.w;
      } else {
#pragma unroll
        for (int j = 0; j < 4; ++j)
          As[(q + j) * SA + r] =
              (grow < M && gk + j < K) ? A[(size_t)grow * lda + gk + j] : 0.f;
      }
    }
    {
      int i = tid;
      int k = i / (BN / 4), cq = (i % (BN / 4)) * 4;
      int gk = kb + k;
      float4 v = {0.f, 0.f, 0.f, 0.f};
      if (gk < K) {
        if (cq + 3 < Nn) {
          v = *(const float4*)(B + (size_t)gk * ldb + cq);
        } else {
#pragma unroll
          for (int j = 0; j < 4; ++j)
            if (cq + j < Nn) (&v.x)[j] = B[(size_t)gk * ldb + cq + j];
        }
      }
      *(float4*)(&Bs[k * SB + cq]) = v;
    }
    __syncthreads();
#pragma unroll
    for (int kk = 0; kk < BK; ++kk) {
      float a[TM], bb[TN];
      *(float4*)(&a[0]) = *(const float4*)(&As[kk * SA + row0]);
      *(float4*)(&bb[0]) = *(const float4*)(&Bs[kk * SB + col0]);
#pragma unroll
      for (int i = 0; i < TM; ++i)
#pragma unroll
        for (int j = 0; j < TN; ++j)
          acc[i][j] += a[i] * bb[j];
    }
    __syncthreads();
  }

  float bcache[TN];
#pragma unroll
  for (int j = 0; j < TN; ++j) bcache[j] = bias[col0 + j];
#pragma unroll
  for (int i = 0; i < TM; ++i) {
    int row = brow + row0 + i;
    if (row >= M) continue;
#pragma unroll
    for (int j = 0; j < TN; ++j)
      C[(size_t)row * ldc + col0 + j] = f2bf(acc[i][j] + bcache[j]);
  }
}

// ---------------- merged hist + weight-prep + poi/road projections ---------
__global__ __launch_bounds__(256) void hist_prep_k(
    const int* __restrict__ dstp, const int* __restrict__ etp,
    int* __restrict__ counts,
    const float* __restrict__ loop_w1, const float* __restrict__ loop_w2,
    const float* __restrict__ time_w,
    const float* __restrict__ coef1, const float* __restrict__ basis1,
    const float* __restrict__ coef2, const float* __restrict__ basis2,
    const float* __restrict__ poi_dist, const float* __restrict__ poi_w,
    const float* __restrict__ poi_b,
    const float* __restrict__ road_feat, const float* __restrict__ road_w,
    const float* __restrict__ road_b,
    unsigned short* __restrict__ Wc1, unsigned short* __restrict__ Wc2,
    unsigned short* __restrict__ TWT, unsigned short* __restrict__ hbuf)
{
  __shared__ __align__(16) char lds[8704];
  int b = blockIdx.x;
  if (b < 2500) {   // histogram: 2500*256 == NE exactly
    int e = b * 256 + threadIdx.x;
    atomicAdd(&counts[dstp[e] * NR + etp[e]], 1);
    return;
  }
  b -= 2500;
  const int to = threadIdx.x & 63;
  const int tq = threadIdx.x >> 6;

  if (b < 378) {
    unsigned short (*T)[66] = (unsigned short (*)[66])lds;
    if (b < 256) {        // Wc[lr][o][r*256+i] = sum_q coef*basis[q][i][o]
      const int lr = b >> 4;
      const int tile = b & 15;
      const int i0 = ((tile >> 2) & 3) * 64, o0 = (tile & 3) * 64;
      const float* coef  = (lr < NR) ? coef1 : coef2;
      const float* basis = (lr < NR) ? basis1 : basis2;
      unsigned short* Wc = (lr < NR) ? Wc1 : Wc2;
      const int r = lr & 7;
      float cf[NB];
#pragma unroll
      for (int q = 0; q < NB; ++q) cf[q] = coef[r * NB + q];
#pragma unroll
      for (int k = 0; k < 16; ++k) {
        int i_loc = tq * 16 + k;
        int i = i0 + i_loc;
        float acc = 0.f;
#pragma unroll
        for (int q = 0; q < NB; ++q)
          acc += cf[q] * basis[((size_t)(q * HID + i)) * HID + o0 + to];
        T[i_loc][to] = f2bf(acc);
      }
      __syncthreads();
#pragma unroll
      for (int k = 0; k < 16; ++k) {
        int o_loc = tq * 16 + k;
        Wc[(size_t)(o0 + o_loc) * KCAT + r * HID + i0 + to] = T[to][o_loc];
      }
    } else if (b < 288) { // Wc[l][o][2048+i] = loop_w_l[i][o]
      const int j = b - 256;
      const int layer = j >> 4;
      const int tile = j & 15;
      const int i0 = ((tile >> 2) & 3) * 64, o0 = (tile & 3) * 64;
      const float* lw = layer ? loop_w2 : loop_w1;
      unsigned short* Wc = layer ? Wc2 : Wc1;
#pragma unroll
      for (int k = 0; k < 16; ++k) {
        int i_loc = tq * 16 + k;
        T[i_loc][to] = f2bf(lw[(size_t)(i0 + i_loc) * HID + o0 + to]);
      }
      __syncthreads();
#pragma unroll
      for (int k = 0; k < 16; ++k) {
        int o_loc = tq * 16 + k;
        Wc[(size_t)(o0 + o_loc) * KCAT + NR * HID + i0 + to] = T[to][o_loc];
      }
    } else {              // TWT[c][r] = time_w[r][c], tiled 64x64
      const int j = b - 288;
      const int r0 = (j >> 1) * 64, c0 = (j & 1) * 64;
#pragma unroll
      for (int k = 0; k < 16; ++k) {
        int r_loc = tq * 16 + k;
        T[r_loc][to] = f2bf(time_w[(size_t)(r0 + r_loc) * 128 + c0 + to]);
      }
      __syncthreads();
#pragma unroll
      for (int k = 0; k < 16; ++k) {
        int c_loc = tq * 16 + k;
        TWT[(size_t)(c0 + c_loc) * KTIME + r0 + to] = T[to][c_loc];
      }
    }
  } else if (b < 691) {   // poi projection -> hbuf cols [0,64)
    sgemm_body(NN, 64, KPOI, poi_dist, KPOI, poi_w, 64, poi_b,
               hbuf + 0, HID, (b - 378) * 64, lds);
  } else {                // road projection -> hbuf cols [192,256)
    sgemm_body(NN, 64, KROAD, road_feat, KROAD, road_w, 64, road_b,
               hbuf + 192, HID, (b - 691) * 64, lds);
  }
}

// ---------------- merged scan: parallel cross-block base -------------------
__global__ __launch_bounds__(256) void scan_all(
    const int* __restrict__ counts, int* __restrict__ offs,
    int* __restrict__ cursor, int* __restrict__ bsums,
    int* __restrict__ counter) {
  __shared__ int sh[256];
  const int bid = blockIdx.x;
  const int t = threadIdx.x;
  const int nblk = gridDim.x;
  const int gbase = bid * 1024;
  int v[4], run[4];
  int s = 0;
#pragma unroll
  for (int j = 0; j < 4; ++j) {
    int idx = gbase + t * 4 + j;
    v[j] = (idx < NK) ? counts[idx] : 0;
    s += v[j];
  }
  sh[t] = s;
  __syncthreads();
  for (int off = 1; off < 256; off <<= 1) {
    int x = (t >= off) ? sh[t - off] : 0;
    __syncthreads();
    sh[t] += x;
    __syncthreads();
  }
  {
    int r = sh[t] - s;
#pragma unroll
    for (int j = 0; j < 4; ++j) { run[j] = r; r += v[j]; }
  }
  if (t == 255) {
    bsums[bid] = sh[255];
    __threadfence();
    atomicAdd(counter, 1);
  }
  if (t == 0) {
    while (atomicAdd(counter, 0) < nblk) {}
    __threadfence();
  }
  __syncthreads();
  int bs = (t < nblk) ? atomicAdd(&bsums[t], 0) : 0;
  __syncthreads();
  sh[t] = bs;
  __syncthreads();
  for (int off = 1; off < 256; off <<= 1) {
    int x = (t >= off) ? sh[t - off] : 0;
    __syncthreads();
    sh[t] += x;
    __syncthreads();
  }
  const int base = (bid > 0) ? sh[bid - 1] : 0;
#pragma unroll
  for (int j = 0; j < 4; ++j) {
    int idx = gbase + t * 4 + j;
    if (idx < NK) {
      int val = run[j] + base;
      offs[idx] = val;
      cursor[idx] = val;
    }
  }
  if (bid == 0 && t == 0) offs[NK] = NE;
}

// ---------------- merged cross-block split-K time GEMM + CSR fill ----------
__global__ __launch_bounds__(256) void time_fill_k(
    const int* __restrict__ srcp, const int* __restrict__ dstp,
    const int* __restrict__ etp, int* __restrict__ cursor,
    unsigned short* __restrict__ ssrc,
    const float* __restrict__ A,            // [NN][2880] f32
    const unsigned short* __restrict__ BT,  // [128][2880] bf16
    float* __restrict__ TP)                 // [SPLITK][NN][128] f32 partials
{
  __shared__ __align__(16) char lds[20480];
  const int b = blockIdx.x;
  const int grp = b / 9, rem = b % 9;
  if (rem >= 5) {   // ---- fill role ----
    int e = (grp * 4 + (rem - 5)) * 256 + threadIdx.x;   // < 640000 exact
    int key = dstp[e] * NR + etp[e];
    int p = atomicAdd(&cursor[key], 1);
    ssrc[p] = (unsigned short)srcp[e];
    return;
  }
  // ---- sk role: rows grp*32..+31, K-chunk rem ----
  char* ldsA = lds;            // 4 KB
  char* ldsB = lds + 4096;     // 16 KB
  const int tid = threadIdx.x;
  const int lane = tid & 63;
  const int w = tid >> 6;            // 0..3 -> col block w*32
  const int brow = grp * 32;
  const int kb0 = rem * KCH;

  f4_t acc[2][2];
#pragma unroll
  for (int i = 0; i < 2; ++i)
#pragma unroll
    for (int j = 0; j < 2; ++j) acc[i][j] = (f4_t){0.f, 0.f, 0.f, 0.f};

  for (int kb = kb0; kb < kb0 + KCH; kb += 64) {
    {  // A: 32 rows x 64 k, f32 -> bf16
      int r = tid >> 3, c8 = tid & 7;
      const float* ap = A + (size_t)(brow + r) * KTIME + kb + c8 * 8;
      f4_t v0 = *(const f4_t*)ap;
      f4_t v1 = *(const f4_t*)(ap + 4);
      unsigned short hh[8];
#pragma unroll
      for (int j = 0; j < 4; ++j) { hh[j] = f2bf(v0[j]); hh[4 + j] = f2bf(v1[j]); }
      *(bf8_t*)(ldsA + r * 128 + ((c8 * 16) ^ ((r & 7) << 4))) = *(bf8_t*)hh;
    }
#pragma unroll
    for (int it = 0; it < 4; ++it) {  // B: 128 rows x 64 k
      int slot = tid + it * 256;
      int r = slot >> 3, c8 = slot & 7;
      bf8_t v = *(const bf8_t*)(BT + (size_t)r * KTIME + kb + c8 * 8);
      *(bf8_t*)(ldsB + r * 128 + ((c8 * 16) ^ ((r & 7) << 4))) = v;
    }
    __syncthreads();
#pragma unroll
    for (int ks = 0; ks < 2; ++ks) {
      const int kbyte = ks * 64 + (lane >> 4) * 16;
      bf8_t af[2], bfr[2];
#pragma unroll
      for (int mi = 0; mi < 2; ++mi) {
        int m = mi * 16 + (lane & 15);
        af[mi] = *(const bf8_t*)(ldsA + m * 128 + (kbyte ^ ((m & 7) << 4)));
      }
#pragma unroll
      for (int ni = 0; ni < 2; ++ni) {
        int n = w * 32 + ni * 16 + (lane & 15);
        bfr[ni] = *(const bf8_t*)(ldsB + n * 128 + (kbyte ^ ((n & 7) << 4)));
      }
#pragma unroll
      for (int mi = 0; mi < 2; ++mi)
#pragma unroll
        for (int ni = 0; ni < 2; ++ni)
          acc[mi][ni] = __builtin_amdgcn_mfma_f32_16x16x32_bf16(
              af[mi], bfr[ni], acc[mi][ni], 0, 0, 0);
    }
    __syncthreads();
  }

  float* tp = TP + (size_t)rem * NN * 128;
  const int rq = (lane >> 4) * 4;
  const int cl = lane & 15;
#pragma unroll
  for (int ni = 0; ni < 2; ++ni) {
    int c = w * 32 + ni * 16 + cl;
#pragma unroll
    for (int mi = 0; mi < 2; ++mi) {
#pragma unroll
      for (int j = 0; j < 4; ++j) {
        int row = brow + mi * 16 + rq + j;
        tp[(size_t)row * 128 + c] = acc[mi][ni][j];
      }
    }
  }
}

// ---------------- time finish: hbuf[:,64:192] = bf16(sum_k TP + bias) ------
__global__ __launch_bounds__(256) void time_finish(
    const float* __restrict__ TP, const float* __restrict__ bias,
    unsigned short* __restrict__ featb) {
  int i = blockIdx.x * 256 + threadIdx.x;   // over NN*32 float4 groups
  if (i >= NN * 32) return;
  int row = i >> 5, c4 = (i & 31) * 4;
  f4_t s = *(const f4_t*)(TP + (size_t)row * 128 + c4);
#pragma unroll
  for (int k = 1; k < SPLITK; ++k) {
    f4_t v = *(const f4_t*)(TP + (size_t)k * NN * 128 + (size_t)row * 128 + c4);
    s.x += v.x; s.y += v.y; s.z += v.z; s.w += v.w;
  }
  f4_t b = *(const f4_t*)(bias + c4);
  unsigned short h[4] = {f2bf(s.x + b.x), f2bf(s.y + b.y),
                         f2bf(s.z + b.z), f2bf(s.w + b.w)};
  *(ushort4*)(featb + (size_t)row * 256 + 64 + c4) = *(ushort4*)h;
}

// ---------------- CSR aggregation: one wave per dst, all 9 slices ----------
__global__ __launch_bounds__(256) void agg_k(
    const int* __restrict__ offs, const unsigned short* __restrict__ ssrc,
    const unsigned short* __restrict__ hin, unsigned short* __restrict__ Zc) {
  int d = (blockIdx.x * 256 + threadIdx.x) >> 6;
  int lane = threadIdx.x & 63;
  if (d >= NN) return;
  unsigned short* zrow = Zc + (size_t)d * KCAT;
  *(ushort4*)(zrow + NR * HID + lane * 4) =
      *(const ushort4*)(hin + (size_t)d * HID + lane * 4);
  int ob[NR + 1];
#pragma unroll
  for (int r = 0; r <= NR; ++r) ob[r] = offs[d * NR + r];
#pragma unroll 1
  for (int q = 0; q < NR; ++q) {
    int e = ob[q], hi = ob[q + 1];
    f4_t az = {0.f, 0.f, 0.f, 0.f};
    for (; e + 4 <= hi; e += 4) {
      int s0 = ssrc[e], s1 = ssrc[e + 1], s2 = ssrc[e + 2], s3 = ssrc[e + 3];
      ushort4 u0 = *(const ushort4*)(hin + (size_t)s0 * HID + lane * 4);
      ushort4 u1 = *(const ushort4*)(hin + (size_t)s1 * HID + lane * 4);
      ushort4 u2 = *(const ushort4*)(hin + (size_t)s2 * HID + lane * 4);
      ushort4 u3 = *(const ushort4*)(hin + (size_t)s3 * HID + lane * 4);
      az.x += (bf2f(u0.x) + bf2f(u1.x)) + (bf2f(u2.x) + bf2f(u3.x));
      az.y += (bf2f(u0.y) + bf2f(u1.y)) + (bf2f(u2.y) + bf2f(u3.y));
      az.z += (bf2f(u0.z) + bf2f(u1.z)) + (bf2f(u2.z) + bf2f(u3.z));
      az.w += (bf2f(u0.w) + bf2f(u1.w)) + (bf2f(u2.w) + bf2f(u3.w));
    }
    for (; e < hi; ++e) {
      int s = ssrc[e];
      ushort4 u = *(const ushort4*)(hin + (size_t)s * HID + lane * 4);
      az.x += bf2f(u.x); az.y += bf2f(u.y);
      az.z += bf2f(u.z); az.w += bf2f(u.w);
    }
    unsigned short hz[4] = {f2bf(az.x), f2bf(az.y), f2bf(az.z), f2bf(az.w)};
    *(ushort4*)(zrow + q * HID + lane * 4) = *(ushort4*)hz;
  }
}

// ---------------- layer GEMM: C[64x256] = Zcat @ Wcat + bias ---------------
// R17-proven single-buffer body + XCD-aware chunked block swizzle (T1).
template<int EPI>
__global__ __launch_bounds__(512) void gemm_cat(
    const unsigned short* __restrict__ Zc,    // [NN][KCAT]
    const unsigned short* __restrict__ Wc,    // [256][KCAT]
    const float* __restrict__ bias,
    float* __restrict__ C, unsigned short* __restrict__ hb)
{
  __shared__ __align__(16) char At[64 * 128];    // 8 KB
  __shared__ __align__(16) char Bt[256 * 128];   // 32 KB
  const int tid = threadIdx.x;
  const int lane = tid & 63;
  const int w = tid >> 6;
  const int wm = w >> 2;         // rows wm*32..+31
  const int wn = w & 3;          // cols wn*64..+63

  // ---- bijective XCD-chunked swizzle (m204): nwg=313, q=39, r=1 ----
  const int nwg = (int)gridDim.x;
  const int q = nwg >> 3, r = nwg & 7;
  const int xcd = blockIdx.x & 7, pos = blockIdx.x >> 3;
  int bswz;
  if (pos < q) bswz = (xcd < r ? xcd * (q + 1) : r * (q + 1) + (xcd - r) * q) + pos;
  else         bswz = (xcd < r ? xcd * (q + 1) + q : nwg);  // only xcd<r valid
  const int brow = bswz * 64;
  const bool full = (brow + 64 <= NN);
  const int c8sw = (lane & 7) ^ (lane >> 3);

  f4_t acc[2][4];
#pragma unroll
  for (int i = 0; i < 2; ++i)
#pragma unroll
    for (int j = 0; j < 4; ++j) acc[i][j] = (f4_t){0.f, 0.f, 0.f, 0.f};

  for (int kb = 0; kb < KCAT; kb += 64) {
    if (full) {  // A via global_load_lds: wave w -> rows w*8..w*8+7
      int row = (w << 3) + (lane >> 3);
      gl_lds16(Zc + (size_t)(brow + row) * KCAT + kb + c8sw * 8,
               At + (w << 10));
    } else {     // guarded reg-staged fallback (last block only)
      int rr = tid >> 3, c8 = tid & 7;
      int grow = brow + rr;
      bf8_t v = {0, 0, 0, 0, 0, 0, 0, 0};
      if (grow < NN) v = *(const bf8_t*)(Zc + (size_t)grow * KCAT + kb + c8 * 8);
      *(bf8_t*)(At + rr * 128 + ((c8 * 16) ^ ((rr & 7) << 4))) = v;
    }
#pragma unroll
    for (int it = 0; it < 4; ++it) {  // B via global_load_lds
      int n0 = (w << 3) + it * 64;
      int n = n0 + (lane >> 3);
      gl_lds16(Wc + (size_t)n * KCAT + kb + c8sw * 8, Bt + n0 * 128);
    }
    __syncthreads();
#pragma unroll
    for (int ks = 0; ks < 2; ++ks) {
      const int kbyte = ks * 64 + (lane >> 4) * 16;
      bf8_t af[2], bfr[4];
#pragma unroll
      for (int mi = 0; mi < 2; ++mi) {
        int m = wm * 32 + mi * 16 + (lane & 15);
        af[mi] = *(const bf8_t*)(At + m * 128 + (kbyte ^ ((m & 7) << 4)));
      }
#pragma unroll
      for (int ni = 0; ni < 4; ++ni) {
        int n = wn * 64 + ni * 16 + (lane & 15);
        bfr[ni] = *(const bf8_t*)(Bt + n * 128 + (kbyte ^ ((n & 7) << 4)));
      }
#pragma unroll
      for (int mi = 0; mi < 2; ++mi)
#pragma unroll
        for (int ni = 0; ni < 4; ++ni)
          acc[mi][ni] = __builtin_amdgcn_mfma_f32_16x16x32_bf16(
              af[mi], bfr[ni], acc[mi][ni], 0, 0, 0);
    }
    __syncthreads();
  }

  const int rq = (lane >> 4) * 4;
  const int cl = lane & 15;
#pragma unroll
  for (int ni = 0; ni < 4; ++ni) {
    int c = wn * 64 + ni * 16 + cl;
    float bv = bias[c];
#pragma unroll
    for (int mi = 0; mi < 2; ++mi) {
#pragma unroll
      for (int j = 0; j < 4; ++j) {
        int row = brow + wm * 32 + mi * 16 + rq + j;
        if (row < NN) {
          size_t o = (size_t)row * HID + c;
          float v = acc[mi][ni][j] + bv;
          if (EPI == 0) C[o] = v;
          else          hb[o] = f2bf(fmaxf(v, 0.f));
        }
      }
    }
  }
}

extern "C" void kernel_launch(void* const* d_in, const int* in_sizes, int n_in,
                              void* d_out, int out_size, void* d_ws, size_t ws_size,
                              hipStream_t stream) {
  const int*   srcp      = (const int*)d_in[0];
  const int*   dstp      = (const int*)d_in[1];
  const int*   etypep    = (const int*)d_in[2];
  const float* poi_dist  = (const float*)d_in[3];
  const float* time_dist = (const float*)d_in[4];
  const float* road_feat = (const float*)d_in[5];
  const float* poi_w     = (const float*)d_in[6];
  const float* poi_b     = (const float*)d_in[7];
  const float* time_w    = (const float*)d_in[8];
  const float* time_b    = (const float*)d_in[9];
  const float* road_w    = (const float*)d_in[10];
  const float* road_b    = (const float*)d_in[11];
  const float* basis1    = (const float*)d_in[12];
  const float* coef1     = (const float*)d_in[13];
  const float* loop_w1   = (const float*)d_in[14];
  const float* bias1     = (const float*)d_in[15];
  const float* basis2    = (const float*)d_in[16];
  const float* coef2     = (const float*)d_in[17];
  const float* loop_w2   = (const float*)d_in[18];
  const float* bias2     = (const float*)d_in[19];

  float* out = (float*)d_out;

  // ws layout (bytes), total ~108.1 MB (ws_size ~921 MB):
  //   Wc1  bf16 @ 0           (1,179,648)   [256][2304]
  //   Wc2  bf16 @ 1,179,648   (1,179,648)
  //   TWT  bf16 @ 2,359,296   (737,280)
  //   hbuf bf16 @ 3,096,576   (10,240,000)  feat; then relu(h1)
  //   Zcat bf16 @ 13,336,576  (92,160,000)  [NN][2304]
  //   offs      @ 105,496,576 (640,016)
  //   bsums     @ 106,136,592 (1,024)
  //   ssrc u16  @ 106,137,616 (1,280,000)
  //   cursor    @ 107,417,616 (640,000)
  // aliases into Zcat region (each dead before Zcat's first write by agg):
  //   counts (NK ints) + counter @ Zcat base; TP f32 (51.2 MB) @ Zcat base
  char* ws = (char*)d_ws;
  unsigned short* Wc1    = (unsigned short*)(ws);
  unsigned short* Wc2    = (unsigned short*)(ws + 1179648);
  unsigned short* TWT    = (unsigned short*)(ws + 2359296);
  unsigned short* hbuf   = (unsigned short*)(ws + 3096576);
  unsigned short* Zcat   = (unsigned short*)(ws + 13336576);
  int*            offs   = (int*)  (ws + 105496576);
  int*            bsums  = (int*)  (ws + 106136592);
  unsigned short* ssrc   = (unsigned short*)(ws + 106137616);
  int*            cursor = (int*)  (ws + 107417616);
  int*            counts = (int*)Zcat;        // NK ints
  int*            counter = counts + NK;      // 1 int (spin counter)
  float*          TP     = (float*)Zcat;      // [SPLITK][NN][128], after scan

  dim3 blk(256);

  // ---- zero counts + counter ----
  hipMemsetAsync(counts, 0, (NK + 1) * sizeof(int), stream);

  // ---- hist (2500 blocks) || weight prep + poi/road projections (1004) ----
  hist_prep_k<<<3504, blk, 0, stream>>>(dstp, etypep, counts,
                                        loop_w1, loop_w2, time_w,
                                        coef1, basis1, coef2, basis2,
                                        poi_dist, poi_w, poi_b,
                                        road_feat, road_w, road_b,
                                        Wc1, Wc2, TWT, hbuf);

  // ---- scan (157 resident blocks, parallel cross-block base) ----
  scan_all<<<(NK + 1023) / 1024, blk, 0, stream>>>(counts, offs, cursor,
                                                   bsums, counter);

  // ---- cross-block split-K time GEMM (3125) || CSR fill (2500), interleaved
  time_fill_k<<<5625, blk, 0, stream>>>(srcp, dstp, etypep, cursor, ssrc,
                                        time_dist, TWT, TP);
  time_finish<<<(NN * 32 + 255) / 256, blk, 0, stream>>>(TP, time_b, hbuf);

  // ---- layer 1 ----
  agg_k<<<NN * 64 / 256, blk, 0, stream>>>(offs, ssrc, hbuf, Zcat);
  gemm_cat<1><<<(NN + 63) / 64, 512, 0, stream>>>(Zcat, Wc1, bias1, nullptr, hbuf);

  // ---- layer 2 ----
  agg_k<<<NN * 64 / 256, blk, 0, stream>>>(offs, ssrc, hbuf, Zcat);
  gemm_cat<0><<<(NN + 63) / 64, 512, 0, stream>>>(Zcat, Wc2, bias2, out, nullptr);
}